// Round 5
// baseline (295.988 us; speedup 1.0000x reference)
//
#include <hip/hip_runtime.h>
#include <hip/hip_bf16.h>

#define NF 128

typedef __attribute__((ext_vector_type(8))) short bf8;
typedef __attribute__((ext_vector_type(4))) float f4;
typedef unsigned short u16x8 __attribute__((ext_vector_type(8)));

static __device__ __forceinline__ unsigned short f2bf(float f) {
  unsigned u = __builtin_bit_cast(unsigned, f);
  u = u + 0x7FFF + ((u >> 16) & 1);            // RNE
  return (unsigned short)(u >> 16);
}

static __device__ __forceinline__ uint4 pkmax4(uint4 a, uint4 b) {
  u16x8 x = __builtin_bit_cast(u16x8, a);
  u16x8 y = __builtin_bit_cast(u16x8, b);
  u16x8 m = __builtin_elementwise_max(x, y);   // v_pk_max_u16: valid for relu'd bf16 (>=0)
  return __builtin_bit_cast(uint4, m);
}

static __device__ __forceinline__ uint4 shflxor4(uint4 a, int m) {
  uint4 r;
  r.x = (unsigned)__shfl_xor((int)a.x, m, 64);
  r.y = (unsigned)__shfl_xor((int)a.y, m, 64);
  r.z = (unsigned)__shfl_xor((int)a.z, m, 64);
  r.w = (unsigned)__shfl_xor((int)a.w, m, 64);
  return r;
}

// ---------------- fp32 -> bf16 convert (X), also zeroes bucket counters ----------------

__global__ void k_convX(const float* __restrict__ A, unsigned short* __restrict__ B,
                        long long nelem, int* __restrict__ bcnt, int nb) {
  long long i = (long long)(blockIdx.x * blockDim.x + threadIdx.x) * 8;
  if (blockIdx.x == 0 && (int)threadIdx.x < nb) bcnt[threadIdx.x] = 0;
  if (i + 8 > nelem) return;
  float4 a = *(const float4*)(A + i);
  float4 b = *(const float4*)(A + i + 4);
  uint4 o;
  o.x = f2bf(a.x) | ((unsigned)f2bf(a.y) << 16);
  o.y = f2bf(a.z) | ((unsigned)f2bf(a.w) << 16);
  o.z = f2bf(b.x) | ((unsigned)f2bf(b.y) << 16);
  o.w = f2bf(b.z) | ((unsigned)f2bf(b.w) << 16);
  *(uint4*)(B + i) = o;
}

// ---------------- pack 6 weight matrices [128][128] f32 -> B-fragment-ordered bf16 ----------------
// unit u = c*64 + lane, c = t*4+kk; elem j = W[kk*32 + (lane>>4)*8 + j][t*16 + (lane&15)]

__global__ void k_packW(const float* W0, const float* W1, const float* W2,
                        const float* W3, const float* W4, const float* W5,
                        unsigned short* __restrict__ out) {
  int gid = blockIdx.x * blockDim.x + threadIdx.x;
  int m = gid >> 11;
  int u = gid & 2047;
  if (m >= 6) return;
  const float* W = (m == 0) ? W0 : (m == 1) ? W1 : (m == 2) ? W2
                 : (m == 3) ? W3 : (m == 4) ? W4 : W5;
  int l = u & 63, c = u >> 6;
  int kk = c & 3, t = c >> 2;
  int kb = kk * 32 + ((l >> 4) << 3);
  int n = t * 16 + (l & 15);
  unsigned short* o = out + (size_t)m * 2048 * 8 + (size_t)u * 8;
  #pragma unroll
  for (int j = 0; j < 8; ++j) o[j] = f2bf(W[(size_t)(kb + j) * NF + n]);
}

// ---------------- CSR build: bucket(256 dsts) 2-pass sort ----------------

#define TILE_B 8192

__global__ __launch_bounds__(256) void k_bhist(const int* __restrict__ dst,
                                               int* __restrict__ bcnt, int E) {
  __shared__ int h[256];
  int tid = threadIdx.x;
  h[tid] = 0;
  __syncthreads();
  int t0 = blockIdx.x * TILE_B;
  int tend = min(E, t0 + TILE_B);
  for (int i = t0 + tid; i < tend; i += 256) atomicAdd(&h[dst[i] >> 8], 1);
  __syncthreads();
  if (h[tid] > 0) atomicAdd(&bcnt[tid], h[tid]);
}

__global__ __launch_bounds__(256) void k_bscan(const int* __restrict__ bcnt,
                                               int* __restrict__ boff,
                                               int* __restrict__ cursors,
                                               int* __restrict__ off,
                                               int nb, int N, int E) {
  __shared__ int sc[256];
  int tid = threadIdx.x;
  int v = (tid < nb) ? bcnt[tid] : 0;
  sc[tid] = v;
  __syncthreads();
  for (int d = 1; d < 256; d <<= 1) {
    int t = (tid >= d) ? sc[tid - d] : 0;
    __syncthreads();
    sc[tid] += t;
    __syncthreads();
  }
  if (tid < nb) {
    boff[tid + 1] = sc[tid];
    cursors[tid] = sc[tid] - v;
  }
  if (tid == 0) { boff[0] = 0; off[N] = E; }
}

// pass B: tile-local counting sort by bucket; bucket id in top 8 bits (src<2^16, NB<=256)
__global__ __launch_bounds__(256) void k_binB(const int* __restrict__ src,
                                              const int* __restrict__ dst,
                                              int* __restrict__ cursors,
                                              unsigned* __restrict__ tmp, int E) {
  __shared__ int h[256], sc[256], gb[256], lc[256];
  __shared__ unsigned sorted[TILE_B];
  int tid = threadIdx.x;
  int t0 = blockIdx.x * TILE_B;
  int tcnt = min(E - t0, TILE_B);
  if (tcnt <= 0) return;
  h[tid] = 0;
  __syncthreads();
  for (int i = tid; i < tcnt; i += 256) atomicAdd(&h[dst[t0 + i] >> 8], 1);
  __syncthreads();
  int v = h[tid];
  sc[tid] = v;
  __syncthreads();
  for (int d = 1; d < 256; d <<= 1) {
    int t = (tid >= d) ? sc[tid - d] : 0;
    __syncthreads();
    sc[tid] += t;
    __syncthreads();
  }
  lc[tid] = 0;
  gb[tid] = (v > 0) ? atomicAdd(&cursors[tid], v) : 0;
  __syncthreads();
  for (int i = tid; i < tcnt; i += 256) {
    int d = dst[t0 + i];
    unsigned s = (unsigned)src[t0 + i];
    int b = d >> 8;
    int p = (sc[b] - h[b]) + atomicAdd(&lc[b], 1);
    sorted[p] = ((unsigned)b << 24) | (s << 8) | (unsigned)(d & 255);
  }
  __syncthreads();
  for (int i = tid; i < tcnt; i += 256) {
    unsigned ev = sorted[i];
    int b = ev >> 24;
    tmp[gb[b] + (i - (sc[b] - h[b]))] = ev & 0xFFFFFFu;
  }
}

// pass C: per-bucket CSR in LDS, coalesced flush; writes off[] and ushort esrc
#define CSR_CAP 15360

__global__ __launch_bounds__(256) void k_binC(const unsigned* __restrict__ tmp,
                                              const int* __restrict__ boff,
                                              int* __restrict__ off,
                                              unsigned short* __restrict__ esrc, int N) {
  __shared__ int lh[256], ls[256], lcur[256];
  __shared__ int csr[CSR_CAP];
  int tid = threadIdx.x;
  int b = blockIdx.x;
  int base = b << 8;
  int beg = boff[b], end = boff[b + 1];
  int cnt = end - beg;
  lh[tid] = 0;
  __syncthreads();
  for (int i = beg + tid; i < end; i += 256) atomicAdd(&lh[tmp[i] & 255], 1);
  __syncthreads();
  int v = lh[tid];
  ls[tid] = v;
  __syncthreads();
  for (int d = 1; d < 256; d <<= 1) {
    int t = (tid >= d) ? ls[tid - d] : 0;
    __syncthreads();
    ls[tid] += t;
    __syncthreads();
  }
  int excl = ls[tid] - v;
  if (base + tid < N) off[base + tid] = beg + excl;
  lcur[tid] = 0;
  __syncthreads();
  if (cnt <= CSR_CAP) {
    for (int i = beg + tid; i < end; i += 256) {
      unsigned e = tmp[i];
      int dl = (int)(e & 255);
      int p = (ls[dl] - lh[dl]) + atomicAdd(&lcur[dl], 1);
      csr[p] = (int)(e >> 8);
    }
    __syncthreads();
    for (int i = tid; i < cnt; i += 256) esrc[beg + i] = (unsigned short)csr[i];
  } else {
    for (int i = beg + tid; i < end; i += 256) {
      unsigned e = tmp[i];
      int dl = (int)(e & 255);
      int p = (ls[dl] - lh[dl]) + atomicAdd(&lcur[dl], 1);
      esrc[beg + p] = (unsigned short)(e >> 8);
    }
  }
}

// ---------------- pool GEMM: Y = relu(A@W + b), W staged in LDS, coalesced store ----------------

__global__ __launch_bounds__(256) void k_gemm_pool(
    const unsigned short* __restrict__ A, const unsigned short* __restrict__ P,
    const float* __restrict__ bias, unsigned short* __restrict__ Yout, int M) {
  __shared__ __align__(16) char smem[32768];
  int tid = threadIdx.x, w = tid >> 6, lane = tid & 63;
  int r0 = lane & 15, g = lane >> 4;
  int base = blockIdx.x * 64;
  int arow = min(base + w * 16 + r0, M - 1);

  {
    uint4* S = (uint4*)smem;
    const uint4* Pv = (const uint4*)P;
    for (int t = tid; t < 2048; t += 256) S[t] = Pv[t];
  }
  __syncthreads();

  f4 acc[8];
  #pragma unroll
  for (int t = 0; t < 8; ++t) acc[t] = (f4){0.f, 0.f, 0.f, 0.f};

  const bf8* Ar = (const bf8*)(A + (size_t)arow * NF);
  const bf8* Wl = (const bf8*)smem;
  #pragma unroll
  for (int kk = 0; kk < 4; ++kk) {
    bf8 a = Ar[kk * 4 + g];
    #pragma unroll
    for (int t = 0; t < 8; ++t) {
      bf8 b = Wl[(t * 4 + kk) * 64 + lane];
      acc[t] = __builtin_amdgcn_mfma_f32_16x16x32_bf16(a, b, acc[t], 0, 0, 0);
    }
  }

  float bb[8];
  #pragma unroll
  for (int t = 0; t < 8; ++t) bb[t] = bias[t * 16 + r0];

  __syncthreads();
  unsigned short* So = (unsigned short*)smem;   // 64x128 bf16 = 16 KB
  #pragma unroll
  for (int i = 0; i < 4; ++i)
    #pragma unroll
    for (int t = 0; t < 8; ++t)
      So[(w * 16 + g * 4 + i) * NF + t * 16 + r0] = f2bf(fmaxf(acc[t][i] + bb[t], 0.f));
  __syncthreads();
  int maxrows = min(64, M - base);
  uint4* Og = (uint4*)(Yout + (size_t)base * NF);
  const uint4* Sv = (const uint4*)smem;
  int maxc = maxrows * 16;
  for (int c = tid; c < 1024; c += 256)
    if (c < maxc) Og[c] = Sv[c];
}

// ---------------- gather-max: one wave per dst node, 4 edges per dwordx4 instr ----------------
// 64 lanes = 4 groups of 16; group g reads a full 256B row of edge (i + j*4 + g).
// Packed u16 max (bf16 >= 0). 4 independent accumulators -> 4 loads in flight.

__global__ __launch_bounds__(256) void k_gather_max(
    const unsigned short* __restrict__ Y, const int* __restrict__ off,
    const unsigned short* __restrict__ esrc, unsigned short* __restrict__ AGG, int N) {
  int w = (blockIdx.x * 256 + threadIdx.x) >> 6;
  int lane = threadIdx.x & 63;
  if (w >= N) return;
  int r0 = lane & 15, g = lane >> 4;
  int s = __builtin_amdgcn_readfirstlane(off[w]);
  int e = __builtin_amdgcn_readfirstlane(off[w + 1]);
  uint4 am[4];
  #pragma unroll
  for (int j = 0; j < 4; ++j) am[j] = (uint4){0u, 0u, 0u, 0u};   // relu >= 0 -> 0 == empty fill
  for (int b0 = s; b0 < e; b0 += 64) {
    int cnt = min(64, e - b0);
    int idxv = (int)esrc[b0 + min(lane, cnt - 1)];   // coalesced ushort block load
    for (int i = 0; i < cnt; i += 16) {
      #pragma unroll
      for (int j = 0; j < 4; ++j) {                  // 4 edges per dwordx4 instr
        int eo = min(i + j * 4 + g, cnt - 1);
        int u = __shfl(idxv, eo, 64);
        uint4 v = *((const uint4*)(Y + (size_t)u * NF) + r0);
        am[j] = pkmax4(am[j], v);
      }
    }
  }
  uint4 a01 = pkmax4(am[0], am[1]);
  uint4 a23 = pkmax4(am[2], am[3]);
  uint4 a = pkmax4(a01, a23);
  a = pkmax4(a, shflxor4(a, 16));
  a = pkmax4(a, shflxor4(a, 32));
  if (g == 0) *(uint4*)(AGG + (size_t)w * NF + r0 * 8) = a;
}

// ---------------- dual GEMM + l2norm + relu: C = norm(A0@W0 + A1@W1 + b) ----------------
// OUT_MODE: 1 = bf16 out, 2 = fp32 out. Both W staged in LDS; smem reused for store staging.

template <int OUT_MODE>
__global__ __launch_bounds__(256) void k_gemm_dual(
    const unsigned short* __restrict__ A0, const unsigned short* __restrict__ P0,
    const unsigned short* __restrict__ A1, const unsigned short* __restrict__ P1,
    const float* __restrict__ bias, void* __restrict__ Cout, int M) {
  __shared__ __align__(16) char smem[65536];
  int tid = threadIdx.x, w = tid >> 6, lane = tid & 63;
  int r0 = lane & 15, g = lane >> 4;
  int base = blockIdx.x * 64;
  int arow = min(base + w * 16 + r0, M - 1);

  {
    uint4* S = (uint4*)smem;
    const uint4* Pv0 = (const uint4*)P0;
    const uint4* Pv1 = (const uint4*)P1;
    for (int t = tid; t < 2048; t += 256) S[t] = Pv0[t];
    for (int t = tid; t < 2048; t += 256) S[2048 + t] = Pv1[t];
  }
  __syncthreads();

  f4 acc[8];
  #pragma unroll
  for (int t = 0; t < 8; ++t) acc[t] = (f4){0.f, 0.f, 0.f, 0.f};

  #pragma unroll
  for (int mat = 0; mat < 2; ++mat) {
    const unsigned short* A = (mat == 0) ? A0 : A1;
    const bf8* Ar = (const bf8*)(A + (size_t)arow * NF);
    const bf8* Wl = (const bf8*)smem + (size_t)mat * 2048;
    #pragma unroll
    for (int kk = 0; kk < 4; ++kk) {
      bf8 a = Ar[kk * 4 + g];
      #pragma unroll
      for (int t = 0; t < 8; ++t) {
        bf8 b = Wl[(t * 4 + kk) * 64 + lane];
        acc[t] = __builtin_amdgcn_mfma_f32_16x16x32_bf16(a, b, acc[t], 0, 0, 0);
      }
    }
  }

  float bb[8];
  #pragma unroll
  for (int t = 0; t < 8; ++t) bb[t] = bias[t * 16 + r0];

  float val[8][4];
  #pragma unroll
  for (int t = 0; t < 8; ++t)
    #pragma unroll
    for (int i = 0; i < 4; ++i) val[t][i] = acc[t][i] + bb[t];

  float ss[4] = {0.f, 0.f, 0.f, 0.f};
  #pragma unroll
  for (int i = 0; i < 4; ++i)
    #pragma unroll
    for (int t = 0; t < 8; ++t) ss[i] += val[t][i] * val[t][i];
  #pragma unroll
  for (int d = 1; d < 16; d <<= 1)
    #pragma unroll
    for (int i = 0; i < 4; ++i) ss[i] += __shfl_xor(ss[i], d, 64);
  float inv[4];
  #pragma unroll
  for (int i = 0; i < 4; ++i) inv[i] = 1.f / fmaxf(sqrtf(ss[i]), 1e-12f);

  __syncthreads();                     // W dead; reuse smem for output staging
  int maxrows = min(64, M - base);

  if (OUT_MODE == 2) {
    float* So = (float*)smem;
    #pragma unroll
    for (int i = 0; i < 4; ++i)
      #pragma unroll
      for (int t = 0; t < 8; ++t)
        So[(w * 16 + g * 4 + i) * NF + t * 16 + r0] = fmaxf(val[t][i] * inv[i], 0.f);
    __syncthreads();
    uint4* Og = (uint4*)((float*)Cout + (size_t)base * NF);
    const uint4* Sv = (const uint4*)smem;
    int maxc = maxrows * 32;
    for (int c = tid; c < 2048; c += 256)
      if (c < maxc) Og[c] = Sv[c];
  } else {
    unsigned short* So = (unsigned short*)smem;
    #pragma unroll
    for (int i = 0; i < 4; ++i)
      #pragma unroll
      for (int t = 0; t < 8; ++t)
        So[(w * 16 + g * 4 + i) * NF + t * 16 + r0] = f2bf(fmaxf(val[t][i] * inv[i], 0.f));
    __syncthreads();
    uint4* Og = (uint4*)((unsigned short*)Cout + (size_t)base * NF);
    const uint4* Sv = (const uint4*)smem;
    int maxc = maxrows * 16;
    for (int c = tid; c < 1024; c += 256)
      if (c < maxc) Og[c] = Sv[c];
  }
}

// ---------------- launch ----------------

extern "C" void kernel_launch(void* const* d_in, const int* in_sizes, int n_in,
                              void* d_out, int out_size, void* d_ws, size_t ws_size,
                              hipStream_t stream) {
  const float* x   = (const float*)d_in[0];
  const int*   src = (const int*)d_in[1];
  const int*   dst = (const int*)d_in[2];
  const float* Wp1 = (const float*)d_in[3];
  const float* bp1 = (const float*)d_in[4];
  const float* Ws1 = (const float*)d_in[5];
  const float* Wn1 = (const float*)d_in[6];
  const float* b1  = (const float*)d_in[7];
  const float* Wp2 = (const float*)d_in[8];
  const float* bp2 = (const float*)d_in[9];
  const float* Ws2 = (const float*)d_in[10];
  const float* Wn2 = (const float*)d_in[11];
  const float* b2  = (const float*)d_in[12];
  float* out = (float*)d_out;

  const int N = in_sizes[0] / NF;
  const int E = in_sizes[1];
  const int NB = (N + 255) >> 8;

  char* ws = (char*)d_ws;
  auto carve = [&](size_t bytes) { char* p = ws; ws += (bytes + 255) & ~(size_t)255; return p; };
  unsigned short* Xb    = (unsigned short*)carve((size_t)N * NF * 2);
  unsigned short* Yb    = (unsigned short*)carve((size_t)N * NF * 2);
  unsigned short* AGGb  = (unsigned short*)carve((size_t)N * NF * 2);
  unsigned short* Hb    = (unsigned short*)carve((size_t)N * NF * 2);
  unsigned short* Wpack = (unsigned short*)carve((size_t)6 * NF * NF * 2);
  int* off     = (int*)carve((size_t)(N + 1) * 4);
  int* bcnt    = (int*)carve((size_t)NB * 4);
  int* boff    = (int*)carve((size_t)(NB + 1) * 4);
  int* cursors = (int*)carve((size_t)NB * 4);
  unsigned* tmp = (unsigned*)carve((size_t)E * 4);
  unsigned short* esrc = (unsigned short*)carve((size_t)E * 2);

  unsigned short* Pp1 = Wpack + 0 * NF * NF;
  unsigned short* Ps1 = Wpack + 1 * NF * NF;
  unsigned short* Pn1 = Wpack + 2 * NF * NF;
  unsigned short* Pp2 = Wpack + 3 * NF * NF;
  unsigned short* Ps2 = Wpack + 4 * NF * NF;
  unsigned short* Pn2 = Wpack + 5 * NF * NF;

  const long long nelX = (long long)N * NF;
  const int gConv = (int)((nelX / 8 + 255) / 256);
  const int gPack = (6 * 2048 + 255) / 256;
  const int gTile = (E + TILE_B - 1) / TILE_B;
  const int gG    = (N + 63) / 64;
  const int gRW   = (N + 3) / 4;

  k_convX<<<gConv, 256, 0, stream>>>(x, Xb, nelX, bcnt, NB);
  k_packW<<<gPack, 256, 0, stream>>>(Wp1, Ws1, Wn1, Wp2, Ws2, Wn2, Wpack);

  k_bhist<<<gTile, 256, 0, stream>>>(dst, bcnt, E);
  k_bscan<<<1, 256, 0, stream>>>(bcnt, boff, cursors, off, NB, N, E);
  k_binB<<<gTile, 256, 0, stream>>>(src, dst, cursors, tmp, E);
  k_binC<<<NB, 256, 0, stream>>>(tmp, boff, off, esrc, N);

  k_gemm_pool<<<gG, 256, 0, stream>>>(Xb, Pp1, bp1, Yb, N);
  k_gather_max<<<gRW, 256, 0, stream>>>(Yb, off, esrc, AGGb, N);
  k_gemm_dual<1><<<gG, 256, 0, stream>>>(Xb, Ps1, AGGb, Pn1, b1, Hb, N);

  k_gemm_pool<<<gG, 256, 0, stream>>>(Hb, Pp2, bp2, Yb, N);
  k_gather_max<<<gRW, 256, 0, stream>>>(Yb, off, esrc, AGGb, N);
  k_gemm_dual<2><<<gG, 256, 0, stream>>>(Hb, Ps2, AGGb, Pn2, b2, out, N);
}